// Round 16
// baseline (578.238 us; speedup 1.0000x reference)
//
#include <hip/hip_runtime.h>

// Problem constants (fixed by reference)
#define BB 256      // batch
#define TT 1024     // time steps
#define HH 32       // hidden
#define SS 16       // superstep length (steps per barrier)
#define NBK (TT/SS) // 64 blocks
#define NSS (NBK+9) // 73 supersteps (10-stage skew)
#define NT 768      // 12 waves, 3/SIMD
#define SP 32       // stream row stride (floats)
#define GP 96       // gi row stride

// R16 = R13 (343us, best) + LDS-pipe relief (falsified: per-SIMD contention
// model, R15 neutral; new model: shared LDS pipe ~1152 broadcast-read instrs
// per superstep is the wall):
//  (1) giA+giB merged per layer -> 3 gi waves, SHARED x b128 reads
//      (ff read-instrs 1152 -> 768, -33% LDS pipe; zero VALU added;
//       scalar wA[32]+wB[32] = same register structure as gh waves, no v2f)
//  (2) NT 1024->768 (12 waves; drops pure-idle waves) with
//      __launch_bounds__(768,3) -> VGPR cap ~168, headroom vs spill cliff.
//
// Superstep n schedule (one barrier per superstep):
//   wv9  : emb gather blk n     -> ebuf
//   wv6  : y1  blk n-1          -> y1s
//   wv7  : y2  blk n-2          -> y2s
//   wv8  : y3  blk n-3          -> y3s
//   wv3  : gi0 (A+B) blk n-4    -> gib[0]
//   wv0  : gh0+gates blk n-5    -> h0s    (16 serial steps, h in regs)
//   wv4  : gi1 (A+B) blk n-6    -> gib[1]
//   wv1  : gh1+gates blk n-7    -> h1s
//   wv5  : gi2 (A+B) blk n-8    -> gib[2]
//   wv2  : gh2+gates blk n-9    -> out_seq (direct store)
//   wv10, wv11 : idle (barrier only)

__device__ __forceinline__ float fast_rcp(float x) { return __builtin_amdgcn_rcpf(x); }
__device__ __forceinline__ float sigm(float x)     { return fast_rcp(1.f + __expf(-x)); }
__device__ __forceinline__ float tanh_fast(float x){ float e = __expf(2.f * x); return 1.f - 2.f * fast_rcp(e + 1.f); }
__device__ __forceinline__ float rlane(float v, int k) {
    return __int_as_float(__builtin_amdgcn_readlane(__float_as_int(v), k));
}

__global__ __launch_bounds__(NT, 3) void rnn_fused(
    const int*   __restrict__ xidx,   // [B,T]
    const float* __restrict__ hid,    // [L,B,H]
    const float* __restrict__ emb,    // [38000,H]
    const float* __restrict__ W1, const float* __restrict__ b1,
    const float* __restrict__ W2, const float* __restrict__ b2,
    const float* __restrict__ W3, const float* __restrict__ b3,
    const float* __restrict__ Wih,    // [L,3H,H]
    const float* __restrict__ Whh,    // [L,3H,H]
    const float* __restrict__ bih,    // [L,3H]
    const float* __restrict__ bhh,    // [L,3H]
    float*       __restrict__ out)    // [B*T*H] ++ [L*B*H]
{
    const int b   = blockIdx.x;
    const int tid = threadIdx.x;
    const int wv  = tid >> 6;
    const int ln  = tid & 63;
    const int lo  = ln & 31;

    __shared__ alignas(16) float ebuf[2][SS][SP];
    __shared__ alignas(16) float y1s [2][SS][SP];
    __shared__ alignas(16) float y2s [2][SS][SP];
    __shared__ alignas(16) float y3s [2][SS][SP];
    __shared__ alignas(16) float h0s [2][SS][SP];
    __shared__ alignas(16) float h1s [2][SS][SP];
    __shared__ alignas(16) float gib [3][2][SS][GP];

    // ---- roles ----
    const bool isGH = (wv < 3);            // layer = wv
    const bool isGI = (wv >= 3 && wv < 6); // merged gi, layer = wv-3
    const int  gl   = wv - 3;
    const bool isY  = (wv >= 6 && wv < 9); // stage = wv-6
    const int  ys   = wv - 6;
    const bool isE  = (wv == 9);

    // ---- register-resident weights (scalar only; gh-proven structure) ----
    float wA[32], wB[32];
    float biasA = 0.f, biasB = 0.f, v_h = 0.f;

    if (isGH) {
        const float4* pA = reinterpret_cast<const float4*>(Whh + (size_t)(wv * 96 + ln) * HH);
        const float4* pB = reinterpret_cast<const float4*>(Whh + (size_t)(wv * 96 + 64 + lo) * HH);
        #pragma unroll
        for (int i = 0; i < 8; ++i) {
            reinterpret_cast<float4*>(wA)[i] = pA[i];
            reinterpret_cast<float4*>(wB)[i] = pB[i];
        }
        biasA = bhh[wv * 96 + ln];
        biasB = bhh[wv * 96 + 64 + lo];
        if (ln < HH) v_h = hid[(size_t)(wv * BB + b) * HH + ln];
    } else if (isGI) {
        const float4* pA = reinterpret_cast<const float4*>(Wih + (size_t)(gl * 96 + ln) * HH);
        const float4* pB = reinterpret_cast<const float4*>(Wih + (size_t)(gl * 96 + 64 + lo) * HH);
        #pragma unroll
        for (int i = 0; i < 8; ++i) {
            reinterpret_cast<float4*>(wA)[i] = pA[i];
            reinterpret_cast<float4*>(wB)[i] = pB[i];
        }
        biasA = bih[gl * 96 + ln];
        biasB = bih[gl * 96 + 64 + lo];
    } else if (isY) {
        const float* Ws = (ys == 0) ? W1 : (ys == 1) ? W2 : W3;
        const float* bs = (ys == 0) ? b1 : (ys == 1) ? b2 : b3;
        const float4* pA = reinterpret_cast<const float4*>(Ws + (size_t)lo * HH);
        #pragma unroll
        for (int i = 0; i < 8; ++i) reinterpret_cast<float4*>(wA)[i] = pA[i];
        biasA = bs[lo];
    }
    __syncthreads();

    float* const out_seq = out + (size_t)b * TT * HH;
    float* const out_hf  = out + (size_t)BB * TT * HH;

    for (int n = 0; n < NSS; ++n) {
        if (isGH) {
            // ============ gh wave, layer wv: 16 serial steps (R13 body) ========
            const int blk = n - 5 - 2 * wv;
            if (blk >= 0 && blk < NBK) {
                const int p = blk & 1;
                const float* gsrc = &gib[wv][p][0][0];
                for (int t2 = 0; t2 < SS; ++t2) {
                    const float giA = gsrc[t2 * GP + ln];        // r/z rows
                    const float giB = gsrc[t2 * GP + 64 + lo];   // n rows
                    float a0 = biasA, a1 = 0.f, c0 = biasB, c1 = 0.f;
                    #pragma unroll
                    for (int k = 0; k < 32; k += 2) {
                        const float h0 = rlane(v_h, k), h1 = rlane(v_h, k + 1);
                        a0 = fmaf(wA[k],     h0, a0);
                        a1 = fmaf(wA[k + 1], h1, a1);
                        c0 = fmaf(wB[k],     h0, c0);
                        c1 = fmaf(wB[k + 1], h1, c1);
                    }
                    const float sA  = giA + a0 + a1;     // r-pre / z-pre
                    const float ghB = c0 + c1;           // h_n
                    const float zp  = __shfl_xor(sA, 32);
                    const float r   = sigm(sA);
                    const float z   = sigm(zp);
                    const float nn  = tanh_fast(fmaf(r, ghB, giB));
                    const float hn  = fmaf(z, v_h - nn, nn);
                    v_h = hn;
                    if (ln < HH) {
                        if (wv == 0)      h0s[p][t2][ln] = hn;
                        else if (wv == 1) h1s[p][t2][ln] = hn;
                        else out_seq[(size_t)(blk * SS + t2) * HH + ln] = hn;
                    }
                }
            }
        } else if (isGI) {
            // ============ merged gi wave, layer gl: SHARED x reads =============
            const int blk = n - 4 - 2 * gl;
            if (blk >= 0 && blk < NBK) {
                const int p = blk & 1;
                const float* xs = (gl == 0) ? &y3s[p][0][0]
                                : (gl == 1) ? &h0s[p][0][0]
                                            : &h1s[p][0][0];
                float* gdst = &gib[gl][p][0][0];
                for (int t2 = 0; t2 < SS; ++t2) {
                    const float4* xr = reinterpret_cast<const float4*>(xs + t2 * SP);
                    float a0 = biasA, a1 = 0.f, a2 = 0.f, a3 = 0.f;
                    float c0 = biasB, c1 = 0.f, c2 = 0.f, c3 = 0.f;
                    #pragma unroll
                    for (int j = 0; j < 8; ++j) {
                        const float4 xv = xr[j];          // uniform addr -> broadcast
                        a0 = fmaf(wA[4 * j + 0], xv.x, a0);
                        a1 = fmaf(wA[4 * j + 1], xv.y, a1);
                        a2 = fmaf(wA[4 * j + 2], xv.z, a2);
                        a3 = fmaf(wA[4 * j + 3], xv.w, a3);
                        c0 = fmaf(wB[4 * j + 0], xv.x, c0);
                        c1 = fmaf(wB[4 * j + 1], xv.y, c1);
                        c2 = fmaf(wB[4 * j + 2], xv.z, c2);
                        c3 = fmaf(wB[4 * j + 3], xv.w, c3);
                    }
                    gdst[t2 * GP + ln] = (a0 + a1) + (a2 + a3);
                    if (ln < 32)
                        gdst[t2 * GP + 64 + ln] = (c0 + c1) + (c2 + c3);
                }
            }
        } else if (isY) {
            // ============ y1/y2/y3 waves (R13 bodies) ==========================
            const int blk = n - 1 - ys;
            if (blk >= 0 && blk < NBK) {
                const int p = blk & 1;
                const float* xs = (ys == 0) ? &ebuf[p][0][0]
                                : (ys == 1) ? &y1s[p][0][0]
                                            : &y2s[p][0][0];
                float* dst = (ys == 0) ? &y1s[p][0][0]
                           : (ys == 1) ? &y2s[p][0][0]
                                       : &y3s[p][0][0];
                for (int t2 = 0; t2 < SS; ++t2) {
                    const float4* xr = reinterpret_cast<const float4*>(xs + t2 * SP);
                    float a0 = biasA, a1 = 0.f, a2 = 0.f, a3 = 0.f;
                    #pragma unroll
                    for (int j = 0; j < 8; ++j) {
                        const float4 xv = xr[j];
                        a0 = fmaf(wA[4 * j + 0], xv.x, a0);
                        a1 = fmaf(wA[4 * j + 1], xv.y, a1);
                        a2 = fmaf(wA[4 * j + 2], xv.z, a2);
                        a3 = fmaf(wA[4 * j + 3], xv.w, a3);
                    }
                    const float y = fmaxf((a0 + a1) + (a2 + a3), 0.f);
                    if (ln < 32) dst[t2 * SP + ln] = y;
                }
            }
        } else if (isE) {
            // ============ emb gather blk n =====================================
            if (n < NBK) {
                const int pe = n & 1, t0 = n * SS;
                #pragma unroll
                for (int k = 0; k < 2; ++k) {
                    const int task = k * 64 + ln;   // 128 tasks: 16 rows x 8 chunks
                    const int row = task >> 3, qq = task & 7;
                    const int tok = xidx[b * TT + t0 + row];
                    const float4 v = *reinterpret_cast<const float4*>(emb + (size_t)tok * HH + qq * 4);
                    *reinterpret_cast<float4*>(&ebuf[pe][row][qq * 4]) = v;
                }
            }
        }
        // wv 10, 11: idle
        __syncthreads();   // one barrier per 16 steps
    }

    if (isGH && ln < HH)
        out_hf[(size_t)(wv * BB + b) * HH + ln] = v_h;
}

extern "C" void kernel_launch(void* const* d_in, const int* in_sizes, int n_in,
                              void* d_out, int out_size, void* d_ws, size_t ws_size,
                              hipStream_t stream) {
    const int*   x   = (const int*)  d_in[0];
    const float* hid = (const float*)d_in[1];
    const float* emb = (const float*)d_in[2];
    const float* W1  = (const float*)d_in[3];
    const float* b1  = (const float*)d_in[4];
    const float* W2  = (const float*)d_in[5];
    const float* b2  = (const float*)d_in[6];
    const float* W3  = (const float*)d_in[7];
    const float* b3  = (const float*)d_in[8];
    const float* Wih = (const float*)d_in[9];
    const float* Whh = (const float*)d_in[10];
    const float* bih = (const float*)d_in[11];
    const float* bhh = (const float*)d_in[12];

    rnn_fused<<<dim3(BB), dim3(NT), 0, stream>>>(
        x, hid, emb, W1, b1, W2, b2, W3, b3, Wih, Whh, bih, bhh, (float*)d_out);
}

// Round 17
// 335.784 us; speedup vs baseline: 1.7221x; 1.7221x over previous
//
#include <hip/hip_runtime.h>

// Problem constants (fixed by reference)
#define BB 256      // batch
#define TT 1024     // time steps
#define HH 32       // hidden
#define SS 16       // superstep length (steps per barrier)
#define NBK (TT/SS) // 64 blocks
#define NSS (NBK+9) // 73 supersteps (10-stage skew)
#define NT 1024     // 16 waves, 4/SIMD
#define SP 32       // stream row stride (floats)
#define GP 96       // gi row stride

// R17 = R13 (343.6us, best; byte-identical structure) + s_setprio(1) around
// the gh serial block ONLY. T5 regime check: superstep schedule is role-
// diverse (serial gh waves vs batch ff waves) -> setprio has something to
// arbitrate (m218b); R15 falsified SIMD-placement contention, R16/R14/R12
// falsified register-structure growth (spill cliff). This is the last
// low-risk lever: issue arbitration for the critical serial wave.
//
// Superstep n schedule (one barrier per superstep):
//   wv12 : emb gather blk n     -> ebuf
//   wv9  : y1  blk n-1          -> y1s
//   wv10 : y2  blk n-2          -> y2s
//   wv11 : y3  blk n-3          -> y3s
//   wv3/6: gi0 A/B blk n-4      -> gib[0]
//   wv0  : gh0+gates blk n-5    -> h0s    (16 serial steps, h in regs, PRIO)
//   wv4/7: gi1 A/B blk n-6      -> gib[1]
//   wv1  : gh1+gates blk n-7    -> h1s                              (PRIO)
//   wv5/8: gi2 A/B blk n-8      -> gib[2]
//   wv2  : gh2+gates blk n-9    -> out_seq (direct store)           (PRIO)
//   wv13-15: idle (barrier only)

__device__ __forceinline__ float fast_rcp(float x) { return __builtin_amdgcn_rcpf(x); }
__device__ __forceinline__ float sigm(float x)     { return fast_rcp(1.f + __expf(-x)); }
__device__ __forceinline__ float tanh_fast(float x){ float e = __expf(2.f * x); return 1.f - 2.f * fast_rcp(e + 1.f); }
__device__ __forceinline__ float rlane(float v, int k) {
    return __int_as_float(__builtin_amdgcn_readlane(__float_as_int(v), k));
}

__global__ __launch_bounds__(NT, 4) void rnn_fused(
    const int*   __restrict__ xidx,   // [B,T]
    const float* __restrict__ hid,    // [L,B,H]
    const float* __restrict__ emb,    // [38000,H]
    const float* __restrict__ W1, const float* __restrict__ b1,
    const float* __restrict__ W2, const float* __restrict__ b2,
    const float* __restrict__ W3, const float* __restrict__ b3,
    const float* __restrict__ Wih,    // [L,3H,H]
    const float* __restrict__ Whh,    // [L,3H,H]
    const float* __restrict__ bih,    // [L,3H]
    const float* __restrict__ bhh,    // [L,3H]
    float*       __restrict__ out)    // [B*T*H] ++ [L*B*H]
{
    const int b   = blockIdx.x;
    const int tid = threadIdx.x;
    const int wv  = tid >> 6;
    const int ln  = tid & 63;
    const int lo  = ln & 31;

    __shared__ alignas(16) float ebuf[2][SS][SP];
    __shared__ alignas(16) float y1s [2][SS][SP];
    __shared__ alignas(16) float y2s [2][SS][SP];
    __shared__ alignas(16) float y3s [2][SS][SP];
    __shared__ alignas(16) float h0s [2][SS][SP];
    __shared__ alignas(16) float h1s [2][SS][SP];
    __shared__ alignas(16) float gib [3][2][SS][GP];

    // ---------------- per-role register-resident weights ----------------
    float wA[32], wB[32];
    float biasA = 0.f, biasB = 0.f, v_h = 0.f;

    if (wv < 3) {                       // gh: Whh rows {ln} and {64+lo}
        const float4* pA = reinterpret_cast<const float4*>(Whh + (size_t)(wv * 96 + ln) * HH);
        const float4* pB = reinterpret_cast<const float4*>(Whh + (size_t)(wv * 96 + 64 + lo) * HH);
        #pragma unroll
        for (int i = 0; i < 8; ++i) {
            reinterpret_cast<float4*>(wA)[i] = pA[i];
            reinterpret_cast<float4*>(wB)[i] = pB[i];
        }
        biasA = bhh[wv * 96 + ln];
        biasB = bhh[wv * 96 + 64 + lo];
        if (ln < HH) v_h = hid[(size_t)(wv * BB + b) * HH + ln];
    } else if (wv < 6) {                // giA: Wih row ln (rows 0-63)
        const int l = wv - 3;
        const float4* pA = reinterpret_cast<const float4*>(Wih + (size_t)(l * 96 + ln) * HH);
        #pragma unroll
        for (int i = 0; i < 8; ++i) reinterpret_cast<float4*>(wA)[i] = pA[i];
        biasA = bih[l * 96 + ln];
    } else if (wv < 9) {                // giB: Wih row 64+lo (rows 64-95)
        const int l = wv - 6;
        const float4* pA = reinterpret_cast<const float4*>(Wih + (size_t)(l * 96 + 64 + lo) * HH);
        #pragma unroll
        for (int i = 0; i < 8; ++i) reinterpret_cast<float4*>(wA)[i] = pA[i];
        biasA = bih[l * 96 + 64 + lo];
    } else if (wv < 12) {               // y1/y2/y3: W row lo
        const float* Ws = (wv == 9) ? W1 : (wv == 10) ? W2 : W3;
        const float* bs = (wv == 9) ? b1 : (wv == 10) ? b2 : b3;
        const float4* pA = reinterpret_cast<const float4*>(Ws + (size_t)lo * HH);
        #pragma unroll
        for (int i = 0; i < 8; ++i) reinterpret_cast<float4*>(wA)[i] = pA[i];
        biasA = bs[lo];
    }
    __syncthreads();

    float* const out_seq = out + (size_t)b * TT * HH;
    float* const out_hf  = out + (size_t)BB * TT * HH;

    for (int n = 0; n < NSS; ++n) {
        if (wv < 3) {
            // ============ gh wave, layer wv: 16 serial recurrence steps ========
            const int blk = n - 5 - 2 * wv;
            if (blk >= 0 && blk < NBK) {
                const int p = blk & 1;
                const float* gsrc = &gib[wv][p][0][0];
                __builtin_amdgcn_s_setprio(1);           // critical serial wave
                for (int t2 = 0; t2 < SS; ++t2) {
                    const float giA = gsrc[t2 * GP + ln];        // r/z rows
                    const float giB = gsrc[t2 * GP + 64 + lo];   // n rows
                    float a0 = biasA, a1 = 0.f, c0 = biasB, c1 = 0.f;
                    #pragma unroll
                    for (int k = 0; k < 32; k += 2) {
                        const float h0 = rlane(v_h, k), h1 = rlane(v_h, k + 1);
                        a0 = fmaf(wA[k],     h0, a0);
                        a1 = fmaf(wA[k + 1], h1, a1);
                        c0 = fmaf(wB[k],     h0, c0);
                        c1 = fmaf(wB[k + 1], h1, c1);
                    }
                    const float sA  = giA + a0 + a1;     // r-pre / z-pre
                    const float ghB = c0 + c1;           // h_n
                    const float zp  = __shfl_xor(sA, 32);
                    const float r   = sigm(sA);
                    const float z   = sigm(zp);
                    const float nn  = tanh_fast(fmaf(r, ghB, giB));
                    const float hn  = fmaf(z, v_h - nn, nn);
                    v_h = hn;
                    if (ln < HH) {
                        if (wv == 0)      h0s[p][t2][ln] = hn;
                        else if (wv == 1) h1s[p][t2][ln] = hn;
                        else out_seq[(size_t)(blk * SS + t2) * HH + ln] = hn;
                    }
                }
                __builtin_amdgcn_s_setprio(0);
            }
        } else if (wv < 6) {
            // ============ giA wave, layer l: rows 0-63, uniform-b128 broadcast =
            const int l   = wv - 3;
            const int blk = n - 4 - 2 * l;
            if (blk >= 0 && blk < NBK) {
                const int p = blk & 1;
                const float* xs = (l == 0) ? &y3s[p][0][0]
                                : (l == 1) ? &h0s[p][0][0]
                                           : &h1s[p][0][0];
                float* gdst = &gib[l][p][0][0];
                for (int t2 = 0; t2 < SS; ++t2) {
                    const float4* xr = reinterpret_cast<const float4*>(xs + t2 * SP);
                    float a0 = biasA, a1 = 0.f, a2 = 0.f, a3 = 0.f;
                    #pragma unroll
                    for (int j = 0; j < 8; ++j) {
                        const float4 xv = xr[j];          // uniform addr -> broadcast
                        a0 = fmaf(wA[4 * j + 0], xv.x, a0);
                        a1 = fmaf(wA[4 * j + 1], xv.y, a1);
                        a2 = fmaf(wA[4 * j + 2], xv.z, a2);
                        a3 = fmaf(wA[4 * j + 3], xv.w, a3);
                    }
                    gdst[t2 * GP + ln] = (a0 + a1) + (a2 + a3);
                }
            }
        } else if (wv < 9) {
            // ============ giB wave, layer l: rows 64-95 (n-gates) ==============
            const int l   = wv - 6;
            const int blk = n - 4 - 2 * l;
            if (blk >= 0 && blk < NBK) {
                const int p = blk & 1;
                const float* xs = (l == 0) ? &y3s[p][0][0]
                                : (l == 1) ? &h0s[p][0][0]
                                           : &h1s[p][0][0];
                float* gdst = &gib[l][p][0][0];
                for (int t2 = 0; t2 < SS; ++t2) {
                    const float4* xr = reinterpret_cast<const float4*>(xs + t2 * SP);
                    float a0 = biasA, a1 = 0.f, a2 = 0.f, a3 = 0.f;
                    #pragma unroll
                    for (int j = 0; j < 8; ++j) {
                        const float4 xv = xr[j];
                        a0 = fmaf(wA[4 * j + 0], xv.x, a0);
                        a1 = fmaf(wA[4 * j + 1], xv.y, a1);
                        a2 = fmaf(wA[4 * j + 2], xv.z, a2);
                        a3 = fmaf(wA[4 * j + 3], xv.w, a3);
                    }
                    if (ln < 32) gdst[t2 * GP + 64 + ln] = (a0 + a1) + (a2 + a3);
                }
            }
        } else if (wv < 12) {
            // ============ y1/y2/y3 waves =======================================
            const int s   = wv - 9;            // 0,1,2
            const int blk = n - 1 - s;
            if (blk >= 0 && blk < NBK) {
                const int p = blk & 1;
                const float* xs = (s == 0) ? &ebuf[p][0][0]
                                : (s == 1) ? &y1s[p][0][0]
                                           : &y2s[p][0][0];
                float* dst = (s == 0) ? &y1s[p][0][0]
                           : (s == 1) ? &y2s[p][0][0]
                                      : &y3s[p][0][0];
                for (int t2 = 0; t2 < SS; ++t2) {
                    const float4* xr = reinterpret_cast<const float4*>(xs + t2 * SP);
                    float a0 = biasA, a1 = 0.f, a2 = 0.f, a3 = 0.f;
                    #pragma unroll
                    for (int j = 0; j < 8; ++j) {
                        const float4 xv = xr[j];
                        a0 = fmaf(wA[4 * j + 0], xv.x, a0);
                        a1 = fmaf(wA[4 * j + 1], xv.y, a1);
                        a2 = fmaf(wA[4 * j + 2], xv.z, a2);
                        a3 = fmaf(wA[4 * j + 3], xv.w, a3);
                    }
                    const float y = fmaxf((a0 + a1) + (a2 + a3), 0.f);
                    if (ln < 32) dst[t2 * SP + ln] = y;
                }
            }
        } else if (wv == 12) {
            // ============ emb gather blk n =====================================
            if (n < NBK) {
                const int pe = n & 1, t0 = n * SS;
                #pragma unroll
                for (int k = 0; k < 2; ++k) {
                    const int task = k * 64 + ln;   // 128 tasks: 16 rows x 8 chunks
                    const int row = task >> 3, qq = task & 7;
                    const int tok = xidx[b * TT + t0 + row];
                    const float4 v = *reinterpret_cast<const float4*>(emb + (size_t)tok * HH + qq * 4);
                    *reinterpret_cast<float4*>(&ebuf[pe][row][qq * 4]) = v;
                }
            }
        }
        // wv 13-15: idle
        __syncthreads();   // one barrier per 16 steps
    }

    if (wv < 3 && ln < HH)
        out_hf[(size_t)(wv * BB + b) * HH + ln] = v_h;
}

extern "C" void kernel_launch(void* const* d_in, const int* in_sizes, int n_in,
                              void* d_out, int out_size, void* d_ws, size_t ws_size,
                              hipStream_t stream) {
    const int*   x   = (const int*)  d_in[0];
    const float* hid = (const float*)d_in[1];
    const float* emb = (const float*)d_in[2];
    const float* W1  = (const float*)d_in[3];
    const float* b1  = (const float*)d_in[4];
    const float* W2  = (const float*)d_in[5];
    const float* b2  = (const float*)d_in[6];
    const float* W3  = (const float*)d_in[7];
    const float* b3  = (const float*)d_in[8];
    const float* Wih = (const float*)d_in[9];
    const float* Whh = (const float*)d_in[10];
    const float* bih = (const float*)d_in[11];
    const float* bhh = (const float*)d_in[12];

    rnn_fused<<<dim3(BB), dim3(NT), 0, stream>>>(
        x, hid, emb, W1, b1, W2, b2, W3, b3, Wih, Whh, bih, bhh, (float*)d_out);
}

// Round 18
// 335.650 us; speedup vs baseline: 1.7227x; 1.0004x over previous
//
#include <hip/hip_runtime.h>

// Problem constants (fixed by reference)
#define BB 256      // batch
#define TT 1024     // time steps
#define HH 32       // hidden
#define SS 16       // superstep length (steps per barrier)
#define NBK (TT/SS) // 64 blocks
#define NSS (NBK+9) // 73 supersteps (10-stage skew)
#define NT 1024     // 16 waves, 4/SIMD
#define SP 32       // stream row stride (floats)
#define GP 96       // gi row stride

// R18 = R17 (335.8us, best) + lane-duplication removal in giB/y waves:
// lanes 0-31 process step 2*t2, lanes 32-63 step 2*t2+1 (iterations 16->8).
// The x b128 read becomes a 2-address wave broadcast (2-way = free, m136);
// all 64 lanes now produce distinct outputs. Zero new registers (spill
// boundary respected: R12/R14/R16 all died to register-structure growth).
// gh (serial, setprio'd), giA, gather: byte-identical to R17.
//
// Superstep n schedule (one barrier per superstep):
//   wv12 : emb gather blk n     -> ebuf
//   wv9  : y1  blk n-1          -> y1s    (2 steps/iter)
//   wv10 : y2  blk n-2          -> y2s    (2 steps/iter)
//   wv11 : y3  blk n-3          -> y3s    (2 steps/iter)
//   wv3/6: gi0 A/B blk n-4      -> gib[0] (B: 2 steps/iter)
//   wv0  : gh0+gates blk n-5    -> h0s    (16 serial steps, PRIO)
//   wv4/7: gi1 A/B blk n-6      -> gib[1]
//   wv1  : gh1+gates blk n-7    -> h1s                        (PRIO)
//   wv5/8: gi2 A/B blk n-8      -> gib[2]
//   wv2  : gh2+gates blk n-9    -> out_seq                    (PRIO)
//   wv13-15: idle (barrier only)

__device__ __forceinline__ float fast_rcp(float x) { return __builtin_amdgcn_rcpf(x); }
__device__ __forceinline__ float sigm(float x)     { return fast_rcp(1.f + __expf(-x)); }
__device__ __forceinline__ float tanh_fast(float x){ float e = __expf(2.f * x); return 1.f - 2.f * fast_rcp(e + 1.f); }
__device__ __forceinline__ float rlane(float v, int k) {
    return __int_as_float(__builtin_amdgcn_readlane(__float_as_int(v), k));
}

__global__ __launch_bounds__(NT, 4) void rnn_fused(
    const int*   __restrict__ xidx,   // [B,T]
    const float* __restrict__ hid,    // [L,B,H]
    const float* __restrict__ emb,    // [38000,H]
    const float* __restrict__ W1, const float* __restrict__ b1,
    const float* __restrict__ W2, const float* __restrict__ b2,
    const float* __restrict__ W3, const float* __restrict__ b3,
    const float* __restrict__ Wih,    // [L,3H,H]
    const float* __restrict__ Whh,    // [L,3H,H]
    const float* __restrict__ bih,    // [L,3H]
    const float* __restrict__ bhh,    // [L,3H]
    float*       __restrict__ out)    // [B*T*H] ++ [L*B*H]
{
    const int b   = blockIdx.x;
    const int tid = threadIdx.x;
    const int wv  = tid >> 6;
    const int ln  = tid & 63;
    const int lo  = ln & 31;
    const int hh  = ln >> 5;           // lane half: step offset for paired waves

    __shared__ alignas(16) float ebuf[2][SS][SP];
    __shared__ alignas(16) float y1s [2][SS][SP];
    __shared__ alignas(16) float y2s [2][SS][SP];
    __shared__ alignas(16) float y3s [2][SS][SP];
    __shared__ alignas(16) float h0s [2][SS][SP];
    __shared__ alignas(16) float h1s [2][SS][SP];
    __shared__ alignas(16) float gib [3][2][SS][GP];

    // ---------------- per-role register-resident weights ----------------
    float wA[32], wB[32];
    float biasA = 0.f, biasB = 0.f, v_h = 0.f;

    if (wv < 3) {                       // gh: Whh rows {ln} and {64+lo}
        const float4* pA = reinterpret_cast<const float4*>(Whh + (size_t)(wv * 96 + ln) * HH);
        const float4* pB = reinterpret_cast<const float4*>(Whh + (size_t)(wv * 96 + 64 + lo) * HH);
        #pragma unroll
        for (int i = 0; i < 8; ++i) {
            reinterpret_cast<float4*>(wA)[i] = pA[i];
            reinterpret_cast<float4*>(wB)[i] = pB[i];
        }
        biasA = bhh[wv * 96 + ln];
        biasB = bhh[wv * 96 + 64 + lo];
        if (ln < HH) v_h = hid[(size_t)(wv * BB + b) * HH + ln];
    } else if (wv < 6) {                // giA: Wih row ln (rows 0-63)
        const int l = wv - 3;
        const float4* pA = reinterpret_cast<const float4*>(Wih + (size_t)(l * 96 + ln) * HH);
        #pragma unroll
        for (int i = 0; i < 8; ++i) reinterpret_cast<float4*>(wA)[i] = pA[i];
        biasA = bih[l * 96 + ln];
    } else if (wv < 9) {                // giB: Wih row 64+lo (n rows; 2 steps/iter)
        const int l = wv - 6;
        const float4* pA = reinterpret_cast<const float4*>(Wih + (size_t)(l * 96 + 64 + lo) * HH);
        #pragma unroll
        for (int i = 0; i < 8; ++i) reinterpret_cast<float4*>(wA)[i] = pA[i];
        biasA = bih[l * 96 + 64 + lo];
    } else if (wv < 12) {               // y1/y2/y3: W row lo (2 steps/iter)
        const float* Ws = (wv == 9) ? W1 : (wv == 10) ? W2 : W3;
        const float* bs = (wv == 9) ? b1 : (wv == 10) ? b2 : b3;
        const float4* pA = reinterpret_cast<const float4*>(Ws + (size_t)lo * HH);
        #pragma unroll
        for (int i = 0; i < 8; ++i) reinterpret_cast<float4*>(wA)[i] = pA[i];
        biasA = bs[lo];
    }
    __syncthreads();

    float* const out_seq = out + (size_t)b * TT * HH;
    float* const out_hf  = out + (size_t)BB * TT * HH;

    for (int n = 0; n < NSS; ++n) {
        if (wv < 3) {
            // ============ gh wave, layer wv: 16 serial recurrence steps ========
            const int blk = n - 5 - 2 * wv;
            if (blk >= 0 && blk < NBK) {
                const int p = blk & 1;
                const float* gsrc = &gib[wv][p][0][0];
                __builtin_amdgcn_s_setprio(1);           // critical serial wave
                for (int t2 = 0; t2 < SS; ++t2) {
                    const float giA = gsrc[t2 * GP + ln];        // r/z rows
                    const float giB = gsrc[t2 * GP + 64 + lo];   // n rows
                    float a0 = biasA, a1 = 0.f, c0 = biasB, c1 = 0.f;
                    #pragma unroll
                    for (int k = 0; k < 32; k += 2) {
                        const float h0 = rlane(v_h, k), h1 = rlane(v_h, k + 1);
                        a0 = fmaf(wA[k],     h0, a0);
                        a1 = fmaf(wA[k + 1], h1, a1);
                        c0 = fmaf(wB[k],     h0, c0);
                        c1 = fmaf(wB[k + 1], h1, c1);
                    }
                    const float sA  = giA + a0 + a1;     // r-pre / z-pre
                    const float ghB = c0 + c1;           // h_n
                    const float zp  = __shfl_xor(sA, 32);
                    const float r   = sigm(sA);
                    const float z   = sigm(zp);
                    const float nn  = tanh_fast(fmaf(r, ghB, giB));
                    const float hn  = fmaf(z, v_h - nn, nn);
                    v_h = hn;
                    if (ln < HH) {
                        if (wv == 0)      h0s[p][t2][ln] = hn;
                        else if (wv == 1) h1s[p][t2][ln] = hn;
                        else out_seq[(size_t)(blk * SS + t2) * HH + ln] = hn;
                    }
                }
                __builtin_amdgcn_s_setprio(0);
            }
        } else if (wv < 6) {
            // ============ giA wave, layer l: rows 0-63, uniform-b128 broadcast =
            const int l   = wv - 3;
            const int blk = n - 4 - 2 * l;
            if (blk >= 0 && blk < NBK) {
                const int p = blk & 1;
                const float* xs = (l == 0) ? &y3s[p][0][0]
                                : (l == 1) ? &h0s[p][0][0]
                                           : &h1s[p][0][0];
                float* gdst = &gib[l][p][0][0];
                for (int t2 = 0; t2 < SS; ++t2) {
                    const float4* xr = reinterpret_cast<const float4*>(xs + t2 * SP);
                    float a0 = biasA, a1 = 0.f, a2 = 0.f, a3 = 0.f;
                    #pragma unroll
                    for (int j = 0; j < 8; ++j) {
                        const float4 xv = xr[j];          // uniform addr -> broadcast
                        a0 = fmaf(wA[4 * j + 0], xv.x, a0);
                        a1 = fmaf(wA[4 * j + 1], xv.y, a1);
                        a2 = fmaf(wA[4 * j + 2], xv.z, a2);
                        a3 = fmaf(wA[4 * j + 3], xv.w, a3);
                    }
                    gdst[t2 * GP + ln] = (a0 + a1) + (a2 + a3);
                }
            }
        } else if (wv < 9) {
            // ============ giB wave, layer l: n rows, 2 steps per iteration =====
            const int l   = wv - 6;
            const int blk = n - 4 - 2 * l;
            if (blk >= 0 && blk < NBK) {
                const int p = blk & 1;
                const float* xs = (l == 0) ? &y3s[p][0][0]
                                : (l == 1) ? &h0s[p][0][0]
                                           : &h1s[p][0][0];
                float* gdst = &gib[l][p][0][0];
                for (int t2 = 0; t2 < SS / 2; ++t2) {
                    const int tt = 2 * t2 + hh;           // half-dependent step
                    const float4* xr = reinterpret_cast<const float4*>(xs + tt * SP);
                    float a0 = biasA, a1 = 0.f, a2 = 0.f, a3 = 0.f;
                    #pragma unroll
                    for (int j = 0; j < 8; ++j) {
                        const float4 xv = xr[j];          // 2-addr broadcast (free)
                        a0 = fmaf(wA[4 * j + 0], xv.x, a0);
                        a1 = fmaf(wA[4 * j + 1], xv.y, a1);
                        a2 = fmaf(wA[4 * j + 2], xv.z, a2);
                        a3 = fmaf(wA[4 * j + 3], xv.w, a3);
                    }
                    gdst[tt * GP + 64 + lo] = (a0 + a1) + (a2 + a3);  // all 64 lanes
                }
            }
        } else if (wv < 12) {
            // ============ y1/y2/y3 waves: 2 steps per iteration ================
            const int s   = wv - 9;            // 0,1,2
            const int blk = n - 1 - s;
            if (blk >= 0 && blk < NBK) {
                const int p = blk & 1;
                const float* xs = (s == 0) ? &ebuf[p][0][0]
                                : (s == 1) ? &y1s[p][0][0]
                                           : &y2s[p][0][0];
                float* dst = (s == 0) ? &y1s[p][0][0]
                           : (s == 1) ? &y2s[p][0][0]
                                      : &y3s[p][0][0];
                for (int t2 = 0; t2 < SS / 2; ++t2) {
                    const int tt = 2 * t2 + hh;           // half-dependent step
                    const float4* xr = reinterpret_cast<const float4*>(xs + tt * SP);
                    float a0 = biasA, a1 = 0.f, a2 = 0.f, a3 = 0.f;
                    #pragma unroll
                    for (int j = 0; j < 8; ++j) {
                        const float4 xv = xr[j];          // 2-addr broadcast (free)
                        a0 = fmaf(wA[4 * j + 0], xv.x, a0);
                        a1 = fmaf(wA[4 * j + 1], xv.y, a1);
                        a2 = fmaf(wA[4 * j + 2], xv.z, a2);
                        a3 = fmaf(wA[4 * j + 3], xv.w, a3);
                    }
                    const float y = fmaxf((a0 + a1) + (a2 + a3), 0.f);
                    dst[tt * SP + lo] = y;                // all 64 lanes store
                }
            }
        } else if (wv == 12) {
            // ============ emb gather blk n =====================================
            if (n < NBK) {
                const int pe = n & 1, t0 = n * SS;
                #pragma unroll
                for (int k = 0; k < 2; ++k) {
                    const int task = k * 64 + ln;   // 128 tasks: 16 rows x 8 chunks
                    const int row = task >> 3, qq = task & 7;
                    const int tok = xidx[b * TT + t0 + row];
                    const float4 v = *reinterpret_cast<const float4*>(emb + (size_t)tok * HH + qq * 4);
                    *reinterpret_cast<float4*>(&ebuf[pe][row][qq * 4]) = v;
                }
            }
        }
        // wv 13-15: idle
        __syncthreads();   // one barrier per 16 steps
    }

    if (wv < 3 && ln < HH)
        out_hf[(size_t)(wv * BB + b) * HH + ln] = v_h;
}

extern "C" void kernel_launch(void* const* d_in, const int* in_sizes, int n_in,
                              void* d_out, int out_size, void* d_ws, size_t ws_size,
                              hipStream_t stream) {
    const int*   x   = (const int*)  d_in[0];
    const float* hid = (const float*)d_in[1];
    const float* emb = (const float*)d_in[2];
    const float* W1  = (const float*)d_in[3];
    const float* b1  = (const float*)d_in[4];
    const float* W2  = (const float*)d_in[5];
    const float* b2  = (const float*)d_in[6];
    const float* W3  = (const float*)d_in[7];
    const float* b3  = (const float*)d_in[8];
    const float* Wih = (const float*)d_in[9];
    const float* Whh = (const float*)d_in[10];
    const float* bih = (const float*)d_in[11];
    const float* bhh = (const float*)d_in[12];

    rnn_fused<<<dim3(BB), dim3(NT), 0, stream>>>(
        x, hid, emb, W1, b1, W2, b2, W3, b3, Wih, Whh, bih, bhh, (float*)d_out);
}